// Round 8
// baseline (140.219 us; speedup 1.0000x reference)
//
#include <hip/hip_runtime.h>
#include <hip/hip_bf16.h>
#include <stdint.h>

#define B_DIM   4096
#define IN_DIM  512
#define OUT_DIM 512
#define M_DIM   16
#define K_DIM   (IN_DIM * M_DIM)     // 8192
#define MN      (B_DIM * OUT_DIM)    // 2097152

typedef unsigned short ushort_t;
typedef __attribute__((ext_vector_type(8))) __bf16 bf16x8;
typedef __attribute__((ext_vector_type(2))) __bf16 bf16x2;
typedef __attribute__((ext_vector_type(4))) float  f32x4;

__device__ __forceinline__ ushort_t f2bf(float f) {
  union { float f; uint32_t u; } v; v.f = f;
  uint32_t u = v.u + 0x7fffu + ((v.u >> 16) & 1u);   // RNE
  return (ushort_t)(u >> 16);
}

// pack two floats -> one u32 of 2 x bf16 (compiler emits v_cvt_pk_bf16_f32)
__device__ __forceinline__ uint32_t pkbf(float lo, float hi) {
  union { bf16x2 h; uint32_t u; } v;
  v.h[0] = (__bf16)lo; v.h[1] = (__bf16)hi;
  return v.u;
}

// force a wave-uniform float into an SGPR
__device__ __forceinline__ float rfl(float f) {
  union { float f; int i; } v; v.f = f;
  v.i = __builtin_amdgcn_readfirstlane(v.i);
  return v.f;
}

// ---------- phase 1: coeffs fp32 -> bf16 (layout [OUT][IN][M] == B^T [N][K]) ----------
#define CONV_N4 (OUT_DIM * K_DIM / 4)
__global__ __launch_bounds__(256) void convert_coeffs_kernel(
    const float* __restrict__ src, ushort_t* __restrict__ dst) {
  int i = blockIdx.x * 256 + threadIdx.x;
  float4 v = ((const float4*)src)[i];
  ushort4 o;
  o.x = f2bf(v.x); o.y = f2bf(v.y); o.z = f2bf(v.z); o.w = f2bf(v.w);
  ((ushort4*)dst)[i] = o;
}

// ---------- phase 2: FUSED basis+GEMM, 2 blocks/CU = 4 waves/SIMD ----------
#define BM 64
#define BN 512
#define BK 32                 // = 2 input-columns x 16 m
#define SPLITK 8
#define KC (K_DIM / SPLITK)   // 1024
#define NITER (KC / BK)       // 32 K-steps
#define XCOLS (KC / M_DIM)    // 64 x-columns per block

#define GLD16(g, l) \
  __builtin_amdgcn_global_load_lds((const __attribute__((address_space(1))) void*)(g), \
                                   (__attribute__((address_space(3))) void*)(l), 16, 0, 0)

template <int ATOMIC>
__global__ __launch_bounds__(512, 4) void gemm_kernel(
    const float* __restrict__ x,      // [B_DIM][IN_DIM] fp32
    const ushort_t* __restrict__ Bt,  // coeffs bf16 [OUT_DIM][K_DIM]
    const float* __restrict__ bc,     // [16][8]
    float* __restrict__ P) {          // partials [SPLITK][B][OUT] or out
  // LDS: As dbuf 8K + Bs dbuf 64K = 72 KiB -> 2 blocks per 160 KiB CU
  __shared__ __align__(16) ushort_t As[2][BM * BK];
  __shared__ __align__(16) ushort_t Bs[2][BN * BK];
  const int tid  = threadIdx.x;
  const int wave = tid >> 6;
  const int lane = tid & 63;
  const int wgid = blockIdx.x;
  const int ks = wgid & 7, bm = wgid >> 3;   // all same-ks blocks -> same XCD, B-slice L2-hot

  // ---- B staging: global_load_lds linear dest, pre-swizzled source slot ----
  const int srow = wave * 16 + (lane >> 2);
  const int scol = (((lane & 3) ^ ((lane >> 3) & 3)) * 8);
  const ushort_t* Bg0 = Bt + (size_t)srow * K_DIM + ks * KC + scol;
  const ushort_t* Bg1 = Bg0 + (size_t)128 * K_DIM;
  const ushort_t* Bg2 = Bg0 + (size_t)256 * K_DIM;
  const ushort_t* Bg3 = Bg0 + (size_t)384 * K_DIM;
  const int bofs0 = (wave * 16) * BK;
  const int bofs1 = (128 + wave * 16) * BK;
  const int bofs2 = (256 + wave * 16) * BK;
  const int bofs3 = (384 + wave * 16) * BK;

#define STAGEB(b) do { \
    GLD16(Bg0, &Bs[b][bofs0]); GLD16(Bg1, &Bs[b][bofs1]); \
    GLD16(Bg2, &Bs[b][bofs2]); GLD16(Bg3, &Bs[b][bofs3]); \
    Bg0 += BK; Bg1 += BK; Bg2 += BK; Bg3 += BK; } while (0)

  // ---- basis production: wave -> m-quartet mq (coeffs SGPR-uniform);
  // thread -> (row, il); 4 basis values per thread per step (ds_write_b64) ----
  const int mq   = wave & 3;                       // m in [mq*4, mq*4+4)
  const int arow = (wave >> 2) * 32 + (lane >> 1); // 0..63
  const int il   = lane & 1;
  const int swz  = (lane >> 2) & 3;                // == (arow>>1)&3
  const int slot16 = il * 2 + (mq >> 1);           // logical 16B slot in BK row
  const int awe  = arow * BK + (((slot16 ^ swz)) << 3) + (mq & 1) * 4;  // ushort idx
  const float* xg = x + (size_t)(bm * BM + arow) * IN_DIM + ks * XCOLS + il;

  float c1[4], c2[4], c3[4], c4[4], c5[4], c6[4], c7[4], c8[4];
  {
    const float* bch = bc + mq * 32;
    #pragma unroll
    for (int m = 0; m < 4; ++m) {
      c1[m] = rfl(bch[m*8+0]); c2[m] = rfl(bch[m*8+1]);
      c3[m] = rfl(bch[m*8+2]); c4[m] = rfl(bch[m*8+3]);
      c5[m] = rfl(bch[m*8+4]); c6[m] = rfl(bch[m*8+5]);
      c7[m] = rfl(bch[m*8+6]); c8[m] = rfl(bch[m*8+7]);
    }
  }

  const float LOG2E = 1.44269504088896340736f;
  const float LN2   = 0.69314718055994530942f;
#define BASIS(pa, xv) do { \
    float xl2 = (xv) * LOG2E; \
    float x2 = (xv) * (xv), x3 = x2 * (xv), x4 = x2 * x2; \
    float ym[4]; \
    _Pragma("unroll") \
    for (int mi = 0; mi < 4; ++mi) { \
      float e     = __builtin_amdgcn_exp2f(c3[mi] * xl2); \
      float inner = e - 1.0f; \
      float p     = __builtin_amdgcn_exp2f(c4[mi] * __builtin_amdgcn_logf(inner)); \
      float u     = LN2 * __builtin_amdgcn_logf(1.0f + p); \
      float vv    = LN2 * __builtin_amdgcn_logf(1.0f + c2[mi] * u); \
      ym[mi] = c1[mi] * vv + c5[mi] * (xv) + c6[mi] * x2 + c7[mi] * x3 + c8[mi] * x4; \
    } \
    *(uint2*)((pa) + awe) = make_uint2(pkbf(ym[0], ym[1]), pkbf(ym[2], ym[3])); \
  } while (0)

  // ---- MFMA geometry: 8 waves as 2x4 grid of 32x128 wave-tiles ----
  const int wr = wave >> 2, wc = wave & 3;
  const int fm = lane & 15;
  const int fkswz = (((lane >> 4) ^ ((lane >> 1) & 3)) << 3);

  f32x4 acc[2][8] = {};

  // split-bfv COMPUTE keeps live fragments at 2+4 regs x4 (reg budget 128)
#define COMPUTE(b) do { \
    bf16x8 af[2]; \
    _Pragma("unroll") \
    for (int t2 = 0; t2 < 2; ++t2) \
      af[t2] = *(const bf16x8*)&As[b][(wr * 32 + t2 * 16 + fm) * BK + fkswz]; \
    _Pragma("unroll") \
    for (int g = 0; g < 2; ++g) { \
      bf16x8 bfv[4]; \
      _Pragma("unroll") \
      for (int u = 0; u < 4; ++u) \
        bfv[u] = *(const bf16x8*)&Bs[b][(wc * 128 + (g * 4 + u) * 16 + fm) * BK + fkswz]; \
      __builtin_amdgcn_s_setprio(1); \
      _Pragma("unroll") \
      for (int mt = 0; mt < 2; ++mt) \
        _Pragma("unroll") \
        for (int nt = 0; nt < 4; ++nt) \
          acc[mt][g * 4 + nt] = __builtin_amdgcn_mfma_f32_16x16x32_bf16(af[mt], bfv[nt], acc[mt][g * 4 + nt], 0, 0, 0); \
      __builtin_amdgcn_s_setprio(0); \
    } \
  } while (0)

  // ---- 2-phase pipeline, 1 barrier/step; x prefetched one step ahead ----
  float xn = xg[0];
  STAGEB(0);
  { float xc = xn; xn = xg[2]; BASIS(&As[0][0], xc); }
  __syncthreads();                        // Bs[0] + As[0] visible
  for (int kt = 0; kt < NITER - 2; kt += 2) {
    STAGEB(1);
    { float xc = xn; xn = xg[2 * (kt + 2)]; COMPUTE(0); BASIS(&As[1][0], xc); }
    __syncthreads();
    STAGEB(0);
    { float xc = xn; xn = xg[2 * (kt + 3)]; COMPUTE(1); BASIS(&As[0][0], xc); }
    __syncthreads();
  }
  STAGEB(1);
  { COMPUTE(0); BASIS(&As[1][0], xn); }   // xn = x for step NITER-1
  __syncthreads();
  COMPUTE(1);

  // ---- epilogue: C/D layout col = lane&15, row = (lane>>4)*4 + reg ----
  const int colb = wc * 128 + fm;
  const int rowb = bm * BM + wr * 32 + (lane >> 4) * 4;
  float* out = P + (ATOMIC ? (size_t)0 : (size_t)ks * MN);
  #pragma unroll
  for (int mt = 0; mt < 2; ++mt) {
    #pragma unroll
    for (int nt = 0; nt < 8; ++nt) {
      #pragma unroll
      for (int j = 0; j < 4; ++j) {
        int row = rowb + mt * 16 + j;
        int col = colb + nt * 16;
        float vv = acc[mt][nt][j];
        if (ATOMIC) atomicAdd(out + (size_t)row * OUT_DIM + col, vv);
        else        out[(size_t)row * OUT_DIM + col] = vv;
      }
    }
  }
#undef STAGEB
#undef BASIS
#undef COMPUTE
}

// ---------- phase 3: reduce split-K partials ----------
__global__ __launch_bounds__(256) void reduce_kernel(
    const float* __restrict__ P, float* __restrict__ out) {
  int i = blockIdx.x * 256 + threadIdx.x;
  const float4* p = (const float4*)P;
  float4 r = p[i];
  #pragma unroll
  for (int s = 1; s < SPLITK; ++s) {
    float4 v = p[i + (size_t)s * (MN / 4)];
    r.x += v.x; r.y += v.y; r.z += v.z; r.w += v.w;
  }
  ((float4*)out)[i] = r;
}

extern "C" void kernel_launch(void* const* d_in, const int* in_sizes, int n_in,
                              void* d_out, int out_size, void* d_ws, size_t ws_size,
                              hipStream_t stream) {
  const float* x      = (const float*)d_in[0];   // [4096][512]
  const float* coeffs = (const float*)d_in[1];   // [512][512][16]
  const float* b_coef = (const float*)d_in[2];   // [16][8]
  float* out = (float*)d_out;
  char*  ws  = (char*)d_ws;

  const size_t COEF_BYTES = (size_t)OUT_DIM * K_DIM * 2;   // 8 MiB
  ushort_t* coefb = (ushort_t*)ws;
  float* partials = (float*)(ws + COEF_BYTES);
  const size_t FULL = COEF_BYTES + (size_t)SPLITK * MN * 4;  // 72 MiB
  const bool use_atomic = (ws_size < FULL);   // deterministic per-session branch

  convert_coeffs_kernel<<<CONV_N4 / 256, 256, 0, stream>>>(coeffs, coefb);

  const int nblk = (B_DIM / BM) * SPLITK;   // 64 x 8 = 512 blocks, 2/CU
  if (use_atomic) {
    hipMemsetAsync(d_out, 0, (size_t)MN * 4, stream);
    gemm_kernel<1><<<nblk, 512, 0, stream>>>(x, coefb, b_coef, out);
  } else {
    gemm_kernel<0><<<nblk, 512, 0, stream>>>(x, coefb, b_coef, partials);
    reduce_kernel<<<MN / 4 / 256, 256, 0, stream>>>(partials, out);
  }
}

// Round 9
// 135.034 us; speedup vs baseline: 1.0384x; 1.0384x over previous
//
#include <hip/hip_runtime.h>
#include <hip/hip_bf16.h>
#include <stdint.h>

#define B_DIM   4096
#define IN_DIM  512
#define OUT_DIM 512
#define M_DIM   16
#define K_DIM   (IN_DIM * M_DIM)     // 8192
#define MN      (B_DIM * OUT_DIM)    // 2097152

typedef unsigned short ushort_t;
typedef __attribute__((ext_vector_type(8))) __bf16 bf16x8;
typedef __attribute__((ext_vector_type(2))) __bf16 bf16x2;
typedef __attribute__((ext_vector_type(4))) float  f32x4;

__device__ __forceinline__ ushort_t f2bf(float f) {
  union { float f; uint32_t u; } v; v.f = f;
  uint32_t u = v.u + 0x7fffu + ((v.u >> 16) & 1u);   // RNE
  return (ushort_t)(u >> 16);
}

// pack two floats -> one u32 of 2 x bf16 (compiler emits v_cvt_pk_bf16_f32)
__device__ __forceinline__ uint32_t pkbf(float lo, float hi) {
  union { bf16x2 h; uint32_t u; } v;
  v.h[0] = (__bf16)lo; v.h[1] = (__bf16)hi;
  return v.u;
}

// force a wave-uniform float into an SGPR
__device__ __forceinline__ float rfl(float f) {
  union { float f; int i; } v; v.f = f;
  v.i = __builtin_amdgcn_readfirstlane(v.i);
  return v.f;
}

// ---------- phase 1: coeffs fp32 -> bf16 (layout [OUT][IN][M] == B^T [N][K]) ----------
#define CONV_N4 (OUT_DIM * K_DIM / 4)
__global__ __launch_bounds__(256) void convert_coeffs_kernel(
    const float* __restrict__ src, ushort_t* __restrict__ dst) {
  int i = blockIdx.x * 256 + threadIdx.x;
  float4 v = ((const float4*)src)[i];
  ushort4 o;
  o.x = f2bf(v.x); o.y = f2bf(v.y); o.z = f2bf(v.z); o.w = f2bf(v.w);
  ((ushort4*)dst)[i] = o;
}

// ---------- phase 2: FUSED basis+GEMM, counted-vmcnt tri-buffer, static unroll ----------
#define BM 128
#define BN 512
#define BK 32                 // = 2 input-columns x 16 m
#define SPLITK 8
#define KC (K_DIM / SPLITK)   // 1024
#define NITER (KC / BK)       // 32 K-steps
#define XCOLS (KC / M_DIM)    // 64 x-columns per block
#define XPAD  129             // row-dim pad for conflict-free reads

#define GLD16(g, l) \
  __builtin_amdgcn_global_load_lds((const __attribute__((address_space(1))) void*)(g), \
                                   (__attribute__((address_space(3))) void*)(l), 16, 0, 0)

// fused counted-wait + barrier in ONE asm: memory ops cannot cross ("memory"
// clobber), but register-only VALU/MFMA remain schedulable around it (no
// sched_barrier pins — m141 showed order-pinning regresses).
#define WAIT_BAR(N) \
  asm volatile("s_waitcnt vmcnt(" #N ") lgkmcnt(0)\n\ts_barrier" ::: "memory")

template <int ATOMIC>
__global__ __launch_bounds__(512, 2) void gemm_kernel(
    const float* __restrict__ x,      // [B_DIM][IN_DIM] fp32
    const ushort_t* __restrict__ Bt,  // coeffs bf16 [OUT_DIM][K_DIM]
    const float* __restrict__ bc,     // [16][8]
    float* __restrict__ P) {          // partials [SPLITK][B][OUT] or out
  // LDS: As dbuf 16K + Bs TRIBUF 96K + Xs 32.25K = 144.25 KiB (1 block/CU)
  __shared__ __align__(16) ushort_t As[2][BM * BK];
  __shared__ __align__(16) ushort_t Bs[3][BN * BK];
  __shared__ __align__(16) float    Xs[XCOLS * XPAD];
  const int tid  = threadIdx.x;
  const int wave = tid >> 6;
  const int lane = tid & 63;
  const int wgid = blockIdx.x;
  const int ks = wgid & 7, bm = wgid >> 3;   // same-ks blocks -> same XCD, B-slice L2-hot

  // ---- x-tile staging (one-time): coalesced float4 loads -> transposed LDS ----
  {
    const int r = tid >> 2, q = tid & 3;
    const float4* xrow = (const float4*)(x + (size_t)(bm * BM + r) * IN_DIM + ks * XCOLS);
    #pragma unroll
    for (int j = 0; j < 4; ++j) {
      float4 v = xrow[q * 4 + j];
      Xs[(q * 16 + j * 4 + 0) * XPAD + r] = v.x;
      Xs[(q * 16 + j * 4 + 1) * XPAD + r] = v.y;
      Xs[(q * 16 + j * 4 + 2) * XPAD + r] = v.z;
      Xs[(q * 16 + j * 4 + 3) * XPAD + r] = v.w;
    }
  }

  // ---- B staging: global_load_lds linear dest, pre-swizzled source slot ----
  const int srow = wave * 16 + (lane >> 2);
  const int scol = (((lane & 3) ^ ((lane >> 3) & 3)) * 8);
  const ushort_t* Bg0 = Bt + (size_t)srow * K_DIM + ks * KC + scol;
  const ushort_t* Bg1 = Bg0 + (size_t)128 * K_DIM;
  const ushort_t* Bg2 = Bg0 + (size_t)256 * K_DIM;
  const ushort_t* Bg3 = Bg0 + (size_t)384 * K_DIM;
  const int bofs0 = (wave * 16) * BK;
  const int bofs1 = (128 + wave * 16) * BK;
  const int bofs2 = (256 + wave * 16) * BK;
  const int bofs3 = (384 + wave * 16) * BK;

  // lb is a compile-time constant at every use (static unroll)
#define STAGEB(lb) do { \
    GLD16(Bg0, &Bs[lb][bofs0]); GLD16(Bg1, &Bs[lb][bofs1]); \
    GLD16(Bg2, &Bs[lb][bofs2]); GLD16(Bg3, &Bs[lb][bofs3]); \
    Bg0 += BK; Bg1 += BK; Bg2 += BK; Bg3 += BK; } while (0)

  // ---- basis production: thread -> (row, i_local, m-half), half wave-uniform ----
  const int half = wave & 1;                       // m in [half*8, half*8+8)
  const int arow = (wave >> 1) * 32 + (lane >> 1); // 0..127
  const int il   = lane & 1;                       // which of 2 input cols in BK
  const int aslot = ((il * 2 + half) ^ ((lane >> 2) & 3));  // XOR-swizzled 16B slot
  const int awe   = arow * BK + aslot * 8;
  const int xbase = il * XPAD + arow;              // Xs[(il+2t)*XPAD + arow]

  const float LOG2E = 1.44269504088896340736f;
  const float LN2   = 0.69314718055994530942f;
  // c1,c2 pre-scaled by LN2 (saves 2 v_mul per eval); kept SGPR via re-readfirstlane
  float c1[8], c2[8], c3[8], c4[8], c5[8], c6[8], c7[8], c8[8];
  {
    const float* bch = bc + half * 64;
    #pragma unroll
    for (int m = 0; m < 8; ++m) {
      c1[m] = rfl(rfl(bch[m*8+0]) * LN2); c2[m] = rfl(rfl(bch[m*8+1]) * LN2);
      c3[m] = rfl(bch[m*8+2]); c4[m] = rfl(bch[m*8+3]);
      c5[m] = rfl(bch[m*8+4]); c6[m] = rfl(bch[m*8+5]);
      c7[m] = rfl(bch[m*8+6]); c8[m] = rfl(bch[m*8+7]);
    }
  }

#define BASIS(ab, t) do { \
    float xv = Xs[xbase + 2 * XPAD * (t)]; \
    float xl2 = xv * LOG2E; \
    float x2 = xv * xv, x3 = x2 * xv, x4 = x2 * x2; \
    float ym[8]; \
    _Pragma("unroll") \
    for (int mi = 0; mi < 8; ++mi) { \
      float e     = __builtin_amdgcn_exp2f(c3[mi] * xl2); \
      float inner = e - 1.0f; \
      float p     = __builtin_amdgcn_exp2f(c4[mi] * __builtin_amdgcn_logf(inner)); \
      float L1    = __builtin_amdgcn_logf(1.0f + p); \
      float vv    = __builtin_amdgcn_logf(1.0f + c2[mi] * L1); \
      ym[mi] = c1[mi] * vv + c5[mi] * xv + c6[mi] * x2 + c7[mi] * x3 + c8[mi] * x4; \
    } \
    *(uint4*)(&As[ab][awe]) = make_uint4(pkbf(ym[0], ym[1]), pkbf(ym[2], ym[3]), \
                                         pkbf(ym[4], ym[5]), pkbf(ym[6], ym[7])); \
  } while (0)

  // ---- MFMA geometry: 8 waves as 2x4 grid of 64x128 wave-tiles ----
  const int wr = wave >> 2, wc = wave & 3;
  const int fm = lane & 15;
  const int fkswz = (((lane >> 4) ^ ((lane >> 1) & 3)) << 3);

  f32x4 acc[4][8] = {};

#define COMPUTE(ab, lb) do { \
    bf16x8 af[4], bfv[8]; \
    _Pragma("unroll") \
    for (int t2 = 0; t2 < 4; ++t2) \
      af[t2] = *(const bf16x8*)&As[ab][(wr * 64 + t2 * 16 + fm) * BK + fkswz]; \
    _Pragma("unroll") \
    for (int u = 0; u < 8; ++u) \
      bfv[u] = *(const bf16x8*)&Bs[lb][(wc * 128 + u * 16 + fm) * BK + fkswz]; \
    __builtin_amdgcn_s_setprio(1); \
    _Pragma("unroll") \
    for (int mt = 0; mt < 4; ++mt) \
      _Pragma("unroll") \
      for (int nt = 0; nt < 8; ++nt) \
        acc[mt][nt] = __builtin_amdgcn_mfma_f32_16x16x32_bf16(af[mt], bfv[nt], acc[mt][nt], 0, 0, 0); \
    __builtin_amdgcn_s_setprio(0); \
  } while (0)

  // one pipeline step, everything compile-time: stage batch t+2, produce As for
  // t+1, compute t; counted vmcnt(4) leaves the just-issued batch in flight.
#define STEP(lbN, ap, ac, lb, t1) do { \
    STAGEB(lbN); BASIS(ap, t1); COMPUTE(ac, lb); WAIT_BAR(4); } while (0)

  // ---- prologue ----
  STAGEB(0); STAGEB(1);
  __syncthreads();              // Xs + Bs[0..1] visible (full drain, once)
  BASIS(0, 0);
  WAIT_BAR(0);                  // As[0] visible

  // ---- main loop: 30 steps, statically unrolled x6 (lb period 3, As parity 2) ----
  for (int tb = 0; tb < NITER - 2; tb += 6) {
    STEP(2, 1, 0, 0, tb + 1);   // t = tb+0
    STEP(0, 0, 1, 1, tb + 2);   // t = tb+1
    STEP(1, 1, 0, 2, tb + 3);   // t = tb+2
    STEP(2, 0, 1, 0, tb + 4);   // t = tb+3
    STEP(0, 1, 0, 1, tb + 5);   // t = tb+4
    STEP(1, 0, 1, 2, tb + 6);   // t = tb+5
  }
  // ---- epilogue: t = 30, 31 (all 32 batches already staged) ----
  BASIS(1, NITER - 1);
  COMPUTE(0, 0);                // t=30: As[0], Bs[30%3=0]
  WAIT_BAR(0);
  COMPUTE(1, 1);                // t=31: As[1], Bs[31%3=1]

  // ---- epilogue: C/D layout col = lane&15, row = (lane>>4)*4 + reg ----
  const int colb = wc * 128 + fm;
  const int rowb = bm * BM + wr * 64 + (lane >> 4) * 4;
  float* out = P + (ATOMIC ? (size_t)0 : (size_t)ks * MN);
  #pragma unroll
  for (int mt = 0; mt < 4; ++mt) {
    #pragma unroll
    for (int nt = 0; nt < 8; ++nt) {
      #pragma unroll
      for (int j = 0; j < 4; ++j) {
        int row = rowb + mt * 16 + j;
        int col = colb + nt * 16;
        float vv = acc[mt][nt][j];
        if (ATOMIC) atomicAdd(out + (size_t)row * OUT_DIM + col, vv);
        else        out[(size_t)row * OUT_DIM + col] = vv;
      }
    }
  }
#undef STAGEB
#undef BASIS
#undef COMPUTE
#undef STEP
}

// ---------- phase 3: reduce split-K partials ----------
__global__ __launch_bounds__(256) void reduce_kernel(
    const float* __restrict__ P, float* __restrict__ out) {
  int i = blockIdx.x * 256 + threadIdx.x;
  const float4* p = (const float4*)P;
  float4 r = p[i];
  #pragma unroll
  for (int s = 1; s < SPLITK; ++s) {
    float4 v = p[i + (size_t)s * (MN / 4)];
    r.x += v.x; r.y += v.y; r.z += v.z; r.w += v.w;
  }
  ((float4*)out)[i] = r;
}

extern "C" void kernel_launch(void* const* d_in, const int* in_sizes, int n_in,
                              void* d_out, int out_size, void* d_ws, size_t ws_size,
                              hipStream_t stream) {
  const float* x      = (const float*)d_in[0];   // [4096][512]
  const float* coeffs = (const float*)d_in[1];   // [512][512][16]
  const float* b_coef = (const float*)d_in[2];   // [16][8]
  float* out = (float*)d_out;
  char*  ws  = (char*)d_ws;

  const size_t COEF_BYTES = (size_t)OUT_DIM * K_DIM * 2;   // 8 MiB
  ushort_t* coefb = (ushort_t*)ws;
  float* partials = (float*)(ws + COEF_BYTES);
  const size_t FULL = COEF_BYTES + (size_t)SPLITK * MN * 4;  // 72 MiB
  const bool use_atomic = (ws_size < FULL);   // deterministic per-session branch

  convert_coeffs_kernel<<<CONV_N4 / 256, 256, 0, stream>>>(coeffs, coefb);

  const int nblk = (B_DIM / BM) * SPLITK;   // 32 x 8 = 256 blocks, 1/CU
  if (use_atomic) {
    hipMemsetAsync(d_out, 0, (size_t)MN * 4, stream);
    gemm_kernel<1><<<nblk, 512, 0, stream>>>(x, coefb, b_coef, out);
  } else {
    gemm_kernel<0><<<nblk, 512, 0, stream>>>(x, coefb, b_coef, partials);
    reduce_kernel<<<MN / 4 / 256, 256, 0, stream>>>(partials, out);
  }
}